// Round 11
// baseline (176.270 us; speedup 1.0000x reference)
//
#include <hip/hip_runtime.h>
#include <hip/hip_bf16.h>

#define N_NODES 8192
#define FIN 512
#define FOUT 64

typedef __attribute__((ext_vector_type(8))) short short8;
typedef __attribute__((ext_vector_type(4))) float floatx4;

static __device__ __forceinline__ short f2bf_bits(float x) {
    union { __hip_bfloat16 b; short s; } u; u.b = __float2bfloat16(x); return u.s;
}

// ---------------------------------------------------------------------------
// Kernel 1: adj (int32 0/1, 256 MB) -> bitmask (8 MB). Pure streaming.
// ~43 µs ≈ 95% of d2d-copy BW — at roofline. Bit-identical to r6/r10.
__global__ __launch_bounds__(256) void adj_bits(
    const int* __restrict__ adj, unsigned long long* __restrict__ bits)
{
    const int lane = threadIdx.x & 63;
    const int wid = blockIdx.x * 4 + (threadIdx.x >> 6);
    const size_t base = (size_t)wid * 128;
    const int* src = adj + base * 64 + lane;
    #pragma unroll 8
    for (int t = 0; t < 128; ++t) {
        int v = src[t * 64];
        unsigned long long m = __ballot(v > 0);
        if (lane == 0) bits[base + t] = m;
    }
}

// ---------------------------------------------------------------------------
// Kernel 2: gat_h — W staged in LDS once per block (the reused operand);
// x streamed via plain per-wave-private coalesced float4 loads (the big
// operand; compiler pipelines them). No DMA, no drains, no per-wave W
// broadcast from global (that was the 110 µs cold-cache pathology).
// Block = 32 rows x 8 waves; wave w owns rows 4w..4w+3.
__global__ __launch_bounds__(512) void gat_h(
    const float* __restrict__ x, const float* __restrict__ W,
    const float* __restrict__ bias, const float* __restrict__ a,
    const float* __restrict__ a_b,
    float2* __restrict__ EFi, float2* __restrict__ EFd,
    unsigned short* __restrict__ hswz)
{
    __shared__ float Wlds[FIN * FOUT];   // 128 KB: W[k][f] row-major

    const int lane = threadIdx.x & 63;
    const int wave = threadIdx.x >> 6;
    const int r0 = blockIdx.x * 32 + wave * 4;

    // cooperative W stage: 8192 float4s over 512 threads = 16 each, coalesced
    {
        const float4* W4 = reinterpret_cast<const float4*>(W);
        float4* L4 = reinterpret_cast<float4*>(Wlds);
        #pragma unroll
        for (int i = 0; i < 16; ++i)
            L4[i * 512 + threadIdx.x] = W4[i * 512 + threadIdx.x];
    }
    __syncthreads();

    const float* xr = x + (size_t)r0 * FIN;
    float acc0 = 0.f, acc1 = 0.f, acc2 = 0.f, acc3 = 0.f;

    #pragma unroll 4
    for (int k4 = 0; k4 < FIN / 4; ++k4) {
        const int kb = k4 * 4;
        // W from LDS: lane f reads Wlds[k*64+f] — 2-way bank alias (free)
        float w0 = Wlds[(kb + 0) * FOUT + lane];
        float w1 = Wlds[(kb + 1) * FOUT + lane];
        float w2 = Wlds[(kb + 2) * FOUT + lane];
        float w3 = Wlds[(kb + 3) * FOUT + lane];
        // x rows private to this wave: plain coalesced float4 loads
        float4 xa = *reinterpret_cast<const float4*>(xr + kb);
        float4 xb = *reinterpret_cast<const float4*>(xr + FIN + kb);
        float4 xc = *reinterpret_cast<const float4*>(xr + 2 * FIN + kb);
        float4 xd = *reinterpret_cast<const float4*>(xr + 3 * FIN + kb);
        acc0 = fmaf(xa.w, w3, fmaf(xa.z, w2, fmaf(xa.y, w1, fmaf(xa.x, w0, acc0))));
        acc1 = fmaf(xb.w, w3, fmaf(xb.z, w2, fmaf(xb.y, w1, fmaf(xb.x, w0, acc1))));
        acc2 = fmaf(xc.w, w3, fmaf(xc.z, w2, fmaf(xc.y, w1, fmaf(xc.x, w0, acc2))));
        acc3 = fmaf(xd.w, w3, fmaf(xd.z, w2, fmaf(xd.y, w1, fmaf(xd.x, w0, acc3))));
    }

    float bb = bias[lane];
    acc0 += bb; acc1 += bb; acc2 += bb; acc3 += bb;

    {   // fragment-major bf16 store (4 rows -> ushort4 at e0 = r0&7)
        const int ks = r0 >> 5;
        const int n = lane >> 4;
        const int lane_dst = (lane & 15) + (((r0 >> 3) & 3) << 4);
        const int e0 = r0 & 7;
        ushort4 pk;
        pk.x = (unsigned short)f2bf_bits(acc0);
        pk.y = (unsigned short)f2bf_bits(acc1);
        pk.z = (unsigned short)f2bf_bits(acc2);
        pk.w = (unsigned short)f2bf_bits(acc3);
        *reinterpret_cast<ushort4*>(
            hswz + (size_t)((ks * 4 + n) * 64 + lane_dst) * 8 + e0) = pk;
    }

    float asrc = a[lane], adst = a[FOUT + lane];
    float ab = a_b[0];
    float ss0 = acc0 * asrc, ss1 = acc1 * asrc, ss2 = acc2 * asrc, ss3 = acc3 * asrc;
    float sd0 = acc0 * adst, sd1 = acc1 * adst, sd2 = acc2 * adst, sd3 = acc3 * adst;
    #pragma unroll
    for (int m = 32; m >= 1; m >>= 1) {
        ss0 += __shfl_xor(ss0, m); ss1 += __shfl_xor(ss1, m);
        ss2 += __shfl_xor(ss2, m); ss3 += __shfl_xor(ss3, m);
        sd0 += __shfl_xor(sd0, m); sd1 += __shfl_xor(sd1, m);
        sd2 += __shfl_xor(sd2, m); sd3 += __shfl_xor(sd3, m);
    }
    if (lane == 0) {
        float si0 = ss0 + ab, si1 = ss1 + ab, si2 = ss2 + ab, si3 = ss3 + ab;
        EFi[r0 + 0] = make_float2(__expf(si0), __expf(0.2f * si0));
        EFi[r0 + 1] = make_float2(__expf(si1), __expf(0.2f * si1));
        EFi[r0 + 2] = make_float2(__expf(si2), __expf(0.2f * si2));
        EFi[r0 + 3] = make_float2(__expf(si3), __expf(0.2f * si3));
        EFd[r0 + 0] = make_float2(__expf(sd0), __expf(0.2f * sd0));
        EFd[r0 + 1] = make_float2(__expf(sd1), __expf(0.2f * sd1));
        EFd[r0 + 2] = make_float2(__expf(sd2), __expf(0.2f * sd2));
        EFd[r0 + 3] = make_float2(__expf(sd3), __expf(0.2f * sd3));
    }
}

// ---------------------------------------------------------------------------
// Kernel 3: gat_attn (bit-identical to r8/r10 validated version).
// p = adj ? (Ei*Ed > 1 ? Ei*Ed : Fi*Fd) : 0 — no exp/lrelu/software-convert.
__global__ __launch_bounds__(512) void gat_attn(
    const unsigned int* __restrict__ bits,
    const float2* __restrict__ EFi,
    const float2* __restrict__ EFd,
    const unsigned short* __restrict__ hswz,
    float* __restrict__ out)
{
    __shared__ __align__(16) char bsmem[16640];   // bits tile, row stride 1040
    __shared__ __align__(16) char rsmem[33280];   // reduction buffers

    const int lane = threadIdx.x & 63;
    const int wave = threadIdx.x >> 6;
    const int i0 = blockIdx.x * 16;
    const int r = lane & 15;
    const int g = lane >> 4;

    #pragma unroll
    for (int i = 0; i < 2; ++i) {
        const int c = threadIdx.x + i * 512;
        const int row = c >> 6, col = c & 63;
        uint4 v = *reinterpret_cast<const uint4*>(bits + (size_t)(i0 + row) * 256 + col * 4);
        *reinterpret_cast<uint4*>(bsmem + row * 1040 + col * 16) = v;
    }
    __syncthreads();

    const float2 efi = EFi[i0 + r];
    const float Es = efi.x, Fs = efi.y;
    const char* bl = bsmem + r * 1040 + (wave << 3);

    floatx4 acc[4] = { {0.f,0.f,0.f,0.f},{0.f,0.f,0.f,0.f},
                       {0.f,0.f,0.f,0.f},{0.f,0.f,0.f,0.f} };
    float denom = 0.f;

    for (int s = 0; s < 16; ++s) {
        uint2 bw = *reinterpret_cast<const uint2*>(bl + s * 64);
        #pragma unroll
        for (int kk = 0; kk < 2; ++kk) {
            const unsigned byte = ((kk ? bw.y : bw.x) >> (g * 8)) & 0xffu;
            const int jb = s * 512 + wave * 64 + kk * 32 + g * 8;
            const float4* ef = reinterpret_cast<const float4*>(EFd + jb);
            float4 q0 = ef[0];
            float4 q1 = ef[1];
            float4 q2 = ef[2];
            float4 q3 = ef[3];
            float m0 = Es * q0.x, f0 = Fs * q0.y;
            float m1 = Es * q0.z, f1 = Fs * q0.w;
            float m2 = Es * q1.x, f2 = Fs * q1.y;
            float m3 = Es * q1.z, f3 = Fs * q1.w;
            float m4 = Es * q2.x, f4 = Fs * q2.y;
            float m5 = Es * q2.z, f5 = Fs * q2.w;
            float m6 = Es * q3.x, f6 = Fs * q3.y;
            float m7 = Es * q3.z, f7 = Fs * q3.w;
            float p0 = m0 > 1.0f ? m0 : f0;  p0 = (byte & 1u)   ? p0 : 0.f;
            float p1 = m1 > 1.0f ? m1 : f1;  p1 = (byte & 2u)   ? p1 : 0.f;
            float p2 = m2 > 1.0f ? m2 : f2;  p2 = (byte & 4u)   ? p2 : 0.f;
            float p3 = m3 > 1.0f ? m3 : f3;  p3 = (byte & 8u)   ? p3 : 0.f;
            float p4 = m4 > 1.0f ? m4 : f4;  p4 = (byte & 16u)  ? p4 : 0.f;
            float p5 = m5 > 1.0f ? m5 : f5;  p5 = (byte & 32u)  ? p5 : 0.f;
            float p6 = m6 > 1.0f ? m6 : f6;  p6 = (byte & 64u)  ? p6 : 0.f;
            float p7 = m7 > 1.0f ? m7 : f7;  p7 = (byte & 128u) ? p7 : 0.f;
            denom += ((p0 + p1) + (p2 + p3)) + ((p4 + p5) + (p6 + p7));
            unsigned r01, r23, r45, r67;
            asm("v_cvt_pk_bf16_f32 %0, %1, %2" : "=v"(r01) : "v"(p0), "v"(p1));
            asm("v_cvt_pk_bf16_f32 %0, %1, %2" : "=v"(r23) : "v"(p2), "v"(p3));
            asm("v_cvt_pk_bf16_f32 %0, %1, %2" : "=v"(r45) : "v"(p4), "v"(p5));
            asm("v_cvt_pk_bf16_f32 %0, %1, %2" : "=v"(r67) : "v"(p6), "v"(p7));
            int4 ai = { (int)r01, (int)r23, (int)r45, (int)r67 };
            short8 af = *reinterpret_cast<short8*>(&ai);
            const int ks = s * 16 + wave * 2 + kk;
            #pragma unroll
            for (int n = 0; n < 4; ++n) {
                short8 bf = *reinterpret_cast<const short8*>(
                    hswz + (size_t)((ks * 4 + n) * 64 + lane) * 8);
                acc[n] = __builtin_amdgcn_mfma_f32_16x16x32_bf16(af, bf, acc[n], 0, 0, 0);
            }
        }
    }

    denom += __shfl_xor(denom, 16);
    denom += __shfl_xor(denom, 32);

    __syncthreads();
    floatx4* redbuf = (floatx4*)rsmem;
    float* dred = (float*)(rsmem + 32768);
    #pragma unroll
    for (int n = 0; n < 4; ++n) redbuf[(wave * 4 + n) * 64 + lane] = acc[n];
    if (lane < 16) dred[wave * 16 + lane] = denom;
    __syncthreads();

    if (wave < 4) {
        floatx4 facc = redbuf[wave * 64 + lane];
        #pragma unroll
        for (int v = 1; v < 8; ++v) facc += redbuf[(v * 4 + wave) * 64 + lane];
        #pragma unroll
        for (int e = 0; e < 4; ++e) {
            const int r2 = (lane >> 4) * 4 + e;
            float dn = 0.f;
            #pragma unroll
            for (int v = 0; v < 8; ++v) dn += dred[v * 16 + r2];
            float val = facc[e] / dn;
            val = val > 0.f ? val : (__expf(val) - 1.f);   // ELU
            out[(size_t)(i0 + r2) * FOUT + wave * 16 + (lane & 15)] = val;
        }
    }
}

extern "C" void kernel_launch(void* const* d_in, const int* in_sizes, int n_in,
                              void* d_out, int out_size, void* d_ws, size_t ws_size,
                              hipStream_t stream) {
    const float* x   = (const float*)d_in[0];
    const int*   adj = (const int*)d_in[1];
    const float* W   = (const float*)d_in[2];
    const float* b   = (const float*)d_in[3];
    const float* a   = (const float*)d_in[4];
    const float* a_b = (const float*)d_in[5];
    float* out = (float*)d_out;

    char* ws = (char*)d_ws;
    float2* EFi = (float2*)ws;                                   // 64 KB
    float2* EFd = (float2*)(ws + 64 * 1024);                     // 64 KB
    unsigned short* hswz = (unsigned short*)(ws + 128 * 1024);   // 1 MB
    unsigned long long* bitsW = (unsigned long long*)(ws + 128 * 1024 + 1024 * 1024); // 8 MB
    const unsigned int* bitsR = (const unsigned int*)bitsW;

    hipLaunchKernelGGL(gat_h, dim3(N_NODES / 32), dim3(512), 0, stream,
                       x, W, b, a, a_b, EFi, EFd, hswz);
    hipLaunchKernelGGL(adj_bits, dim3(N_NODES / 4), dim3(256), 0, stream, adj, bitsW);
    hipLaunchKernelGGL(gat_attn, dim3(N_NODES / 16), dim3(512), 0, stream,
                       bitsR, EFi, EFd, hswz, out);
}